// Round 14
// baseline (126.309 us; speedup 1.0000x reference)
//
#include <hip/hip_runtime.h>
#include <math.h>

#define NTHREADS 512
#define BR 64

typedef __attribute__((ext_vector_type(8))) short short8;
typedef __attribute__((ext_vector_type(4))) float f32x4;

// packed-weight channel layout (shorts): [0,4096) W1' | [4096,20480) W2 | [20480,69632) W3
#define W1OFF 0
#define W2OFF 4096
#define W3OFF 20480
#define WCH   69632      // shorts per channel (hi at +0, lo at +WCH)
// b1' (128 floats) at ws + 2*WCH shorts; b3' (384 floats) right after.
// ws total = 2*69632*2 + 512 + 1536 = 280576 B.

__device__ __forceinline__ unsigned short f2bf(float f) {
    unsigned u = __float_as_uint(f);
    u += 0x7fffu + ((u >> 16) & 1u);          // RNE
    return (unsigned short)(u >> 16);
}
__device__ __forceinline__ float bf2f(unsigned short h) {
    return __uint_as_float(((unsigned)h) << 16);
}
__device__ __forceinline__ float frcp(float x) { return __builtin_amdgcn_rcpf(x); }
__device__ __forceinline__ float max3f(float a, float b, float c) {
    return fmaxf(fmaxf(a, b), c);             // fuses to v_max3_f32; exactly associative
}
// truncated hi/lo split: hi = top 16 bits, lo = exact residual truncated
__device__ __forceinline__ void split2(float v, unsigned short& hi, unsigned short& lo) {
    unsigned u = __float_as_uint(v);
    hi = (unsigned short)(u >> 16);
    float lof = v - __uint_as_float(u & 0xFFFF0000u);
    lo = (unsigned short)(__float_as_uint(lof) >> 16);
}

// ---- prep: pack W1'=diag(s)W1 (16x128, K-pad 32), W2 (128x128), W3 (128x376->384
//      in 48-stride-per-dim layout) as bf16 hi/lo MFMA B-fragments; b1', b3' precomputed.
// dst for B[k][n]: base + tileIdx*512 + ((k&31)>>3)*128 + (n&15)*8 + (k&7)
__global__ void pack_weights(const float* __restrict__ W1, const float* __restrict__ W2,
                             const float* __restrict__ W3,
                             const float* __restrict__ bn_scale, const float* __restrict__ bn_bias,
                             const float* __restrict__ bn_mean, const float* __restrict__ bn_var,
                             const float* __restrict__ b1, const float* __restrict__ b3,
                             unsigned short* __restrict__ ws) {
    int idx = blockIdx.x * blockDim.x + threadIdx.x;
    if (idx >= 70144) return;
    if (idx >= 69760) {                        // b3' in 48-stride layout (pad cols -> 0)
        int n = idx - 69760;                   // n < 384
        int j = n & 47;
        ((float*)(ws + 2 * WCH))[128 + n] = (j < 47) ? b3[(n >> 4) / 3 * 47 + j] : 0.0f;
        return;
    }
    if (idx >= 69632) {                        // b1' = b1 + sum_k t_k W1[k][n]
        int n = idx - 69632;                   // n < 128
        float acc = b1[n];
        for (int k = 0; k < 16; ++k) {
            float s = bn_scale[k] * rsqrtf(bn_var[k] + 1e-5f);
            float t = bn_bias[k] - bn_mean[k] * s;
            acc += t * W1[k * 128 + n];
        }
        ((float*)(ws + 2 * WCH))[n] = acc;
        return;
    }
    int k, n, tileIdx, base;
    float v;
    if (idx < 4096) {                // W1': 32x128 (k>=16 zero), scaled by s_k
        k = idx >> 7; n = idx & 127;
        if (k < 16) {
            float s = bn_scale[k] * rsqrtf(bn_var[k] + 1e-5f);
            v = s * W1[k * 128 + n];
        } else v = 0.0f;
        base = W1OFF; tileIdx = (n >> 4);
    } else if (idx < 20480) {        // W2: 128x128
        int j = idx - 4096; k = j >> 7; n = j & 127;
        v = W2[k * 128 + n];
        base = W2OFF; tileIdx = (k >> 5) * 8 + (n >> 4);
    } else {                         // W3: 128x384, col c -> source (c/48)*47 + c%48
        int j = idx - 20480; k = j / 384; n = j - k * 384;
        int jj = n % 48, dd = n / 48;
        v = (jj < 47) ? W3[k * 376 + dd * 47 + jj] : 0.0f;
        base = W3OFF; tileIdx = (k >> 5) * 24 + (n >> 4);
    }
    int dst = base + tileIdx * 512 + ((k & 31) >> 3) * 128 + (n & 15) * 8 + (k & 7);
    unsigned short hi = f2bf(v);
    unsigned short lo = f2bf(v - bf2f(hi));
    ws[dst]       = hi;
    ws[dst + WCH] = lo;
}

// A-fragment from swizzled LDS tile h[row][128] bf16 (row stride 256B), rows 0..63
__device__ __forceinline__ short8 ldsA(const unsigned short* h, int mt, int kt, int lane) {
    int row  = mt * 16 + (lane & 15);
    int byte = row * 256 + kt * 64 + ((lane >> 4) << 4);
    byte ^= (row & 7) << 4;
    return *reinterpret_cast<const short8*>(reinterpret_cast<const char*>(h) + byte);
}
// A-fragment from h0 [64 rows][40 shorts] (K=32 used), row stride 80B
__device__ __forceinline__ short8 ldsA0(const unsigned short* h, int mt, int lane) {
    int row  = mt * 16 + (lane & 15);
    int byte = row * 80 + ((lane >> 4) << 4);
    return *reinterpret_cast<const short8*>(reinterpret_cast<const char*>(h) + byte);
}
__device__ __forceinline__ short8 ldB(const unsigned short* w, int tileIdx, int lane) {
    return *reinterpret_cast<const short8*>(w + (tileIdx * 64 + lane) * 8);
}
__device__ __forceinline__ void stH(unsigned short* h, int row, int col, unsigned short v) {
    int byte = row * 256 + col * 2;
    byte ^= (row & 7) << 4;
    *reinterpret_cast<unsigned short*>(reinterpret_cast<char*>(h) + byte) = v;
}

__global__ __launch_bounds__(NTHREADS, 4)
void nsc_mfma(const float* __restrict__ x, const float* __restrict__ c,
              const float* __restrict__ b2,
              const unsigned short* __restrict__ wpk,
              float* __restrict__ out, int N)
{
    // LDS overlays (48 KB total):
    //   [0,16384)+[16384,32768)  h1hi/h1lo  (L1-write / L2-read)
    //   same region              h2hi/h2lo  (L2-write after read-barrier / L3-read)
    //   [32768,37888)+[37888,43008)  h0hi/h0lo  (phase A / L1; dead after)
    //   [0,49152)                h3 f16 64 x 384, row 768B, XOR-swz (row&7)<<4
    __shared__ __align__(16) char smem[49152];
    unsigned short* h1hi = (unsigned short*)(smem);
    unsigned short* h1lo = (unsigned short*)(smem + 16384);
    unsigned short* h2hi = (unsigned short*)(smem);           // overlays h1 (read-barrier'd)
    unsigned short* h2lo = (unsigned short*)(smem + 16384);
    unsigned short* h0hi = (unsigned short*)(smem + 32768);
    unsigned short* h0lo = (unsigned short*)(smem + 37888);

    const unsigned short* wlo = wpk + WCH;
    const float* b1p = (const float*)(wpk + 2 * WCH);
    const float* b3p = b1p + 128;

    const int tid  = threadIdx.x;
    const int lane = tid & 63;
    const int wv   = tid >> 6;        // 8 waves; each wave covers M=64 (all 4 mt) x N/8
    const int row0 = blockIdx.x * BR;

    // ---- Phase A (vectorized): h0 = raw hstack([upper, c]) -> bf16 hi/lo ----
    {
        const int r  = tid >> 3;      // 0..63
        const int p  = tid & 7;       // col-pair index: cols 2p, 2p+1
        int row = row0 + r; if (row >= N) row = N - 1;
        const float2 v2 = (p < 4)
            ? *reinterpret_cast<const float2*>(x + row * 16 + 8 + 2 * p)
            : *reinterpret_cast<const float2*>(c + row * 8 + 2 * (p - 4));
        unsigned short hi0, lo0, hi1, lo1;
        split2(v2.x, hi0, lo0);
        split2(v2.y, hi1, lo1);
        const int base = r * 40 + 2 * p;
        *reinterpret_cast<unsigned*>(h0hi + base) = (unsigned)hi0 | ((unsigned)hi1 << 16);
        *reinterpret_cast<unsigned*>(h0lo + base) = (unsigned)lo0 | ((unsigned)lo1 << 16);
        *reinterpret_cast<unsigned*>(h0hi + base + 16) = 0u;   // K pad cols 16..31
        *reinterpret_cast<unsigned*>(h0lo + base + 16) = 0u;
    }
    __syncthreads();

    // ---- Layer 1 (MFMA split): h1 = swish(h0 @ W1' + b1'), bias in acc init ----
    {
        const int col = wv * 16 + (lane & 15);
        const float bias = b1p[col];
        f32x4 acc[4];
        #pragma unroll
        for (int m = 0; m < 4; ++m) acc[m] = (f32x4){bias, bias, bias, bias};
        short8 bhi = ldB(wpk + W1OFF, wv, lane);
        short8 blo = ldB(wlo + W1OFF, wv, lane);
        __builtin_amdgcn_s_setprio(1);
        #pragma unroll
        for (int m = 0; m < 4; ++m) {
            short8 ahi = ldsA0(h0hi, m, lane);
            short8 alo = ldsA0(h0lo, m, lane);
            acc[m] = __builtin_amdgcn_mfma_f32_16x16x32_bf16(alo, bhi, acc[m], 0, 0, 0);
            acc[m] = __builtin_amdgcn_mfma_f32_16x16x32_bf16(ahi, blo, acc[m], 0, 0, 0);
            acc[m] = __builtin_amdgcn_mfma_f32_16x16x32_bf16(ahi, bhi, acc[m], 0, 0, 0);
        }
        __builtin_amdgcn_s_setprio(0);
        #pragma unroll
        for (int m = 0; m < 4; ++m) {
            #pragma unroll
            for (int r = 0; r < 4; ++r) {
                const int row = m * 16 + (lane >> 4) * 4 + r;
                float v = acc[m][r];
                v = v * frcp(1.0f + __expf(-v));
                unsigned short hi, lo; split2(v, hi, lo);
                stH(h1hi, row, col, hi);
                stH(h1lo, row, col, lo);
            }
        }
    }
    __syncthreads();   // h1 ready; h0 dead after L1's reads

    // ---- Layer 2 (MFMA split): h2 = swish(h1 @ W2 + b2); h2 OVERLAYS h1 after read-barrier ----
    {
        const int col = wv * 16 + (lane & 15);
        const float bias = b2[col];
        f32x4 acc[4];
        #pragma unroll
        for (int m = 0; m < 4; ++m) acc[m] = (f32x4){bias, bias, bias, bias};
        __builtin_amdgcn_s_setprio(1);
        #pragma unroll
        for (int kt = 0; kt < 4; ++kt) {
            short8 bhi = ldB(wpk + W2OFF, kt * 8 + wv, lane);
            short8 blo = ldB(wlo + W2OFF, kt * 8 + wv, lane);
            #pragma unroll
            for (int m = 0; m < 4; ++m) {
                short8 ahi = ldsA(h1hi, m, kt, lane);
                short8 alo = ldsA(h1lo, m, kt, lane);
                acc[m] = __builtin_amdgcn_mfma_f32_16x16x32_bf16(alo, bhi, acc[m], 0, 0, 0);
                acc[m] = __builtin_amdgcn_mfma_f32_16x16x32_bf16(ahi, blo, acc[m], 0, 0, 0);
                acc[m] = __builtin_amdgcn_mfma_f32_16x16x32_bf16(ahi, bhi, acc[m], 0, 0, 0);
            }
        }
        __builtin_amdgcn_s_setprio(0);
        __syncthreads();   // ALL waves done reading h1 -> h2 may overwrite the region
        #pragma unroll
        for (int m = 0; m < 4; ++m) {
            #pragma unroll
            for (int r = 0; r < 4; ++r) {
                const int row = m * 16 + (lane >> 4) * 4 + r;
                float v = acc[m][r];
                v = v * frcp(1.0f + __expf(-v));
                unsigned short hi, lo; split2(v, hi, lo);
                stH(h2hi, row, col, hi);
                stH(h2lo, row, col, lo);
            }
        }
    }
    __syncthreads();

    // ---- Layer 3 (MFMA split): M=64/wave, nt = wv*3+{0..2}; bias in acc init ----
    {
        const int nt0 = wv * 3;
        float biasv[3];
        #pragma unroll
        for (int i = 0; i < 3; ++i) biasv[i] = b3p[(nt0 + i) * 16 + (lane & 15)];
        f32x4 acc[4][3];
        #pragma unroll
        for (int m = 0; m < 4; ++m)
            #pragma unroll
            for (int i = 0; i < 3; ++i)
                acc[m][i] = (f32x4){biasv[i], biasv[i], biasv[i], biasv[i]};
        __builtin_amdgcn_s_setprio(1);
        #pragma unroll
        for (int kt = 0; kt < 4; ++kt) {
            short8 ahi[4], alo[4];
            #pragma unroll
            for (int m = 0; m < 4; ++m) { ahi[m] = ldsA(h2hi, m, kt, lane); alo[m] = ldsA(h2lo, m, kt, lane); }
            #pragma unroll
            for (int i = 0; i < 3; ++i) {
                const int t = kt * 24 + nt0 + i;
                short8 bhi = ldB(wpk + W3OFF, t, lane);
                short8 blo = ldB(wlo + W3OFF, t, lane);
                #pragma unroll
                for (int m = 0; m < 4; ++m) {
                    acc[m][i] = __builtin_amdgcn_mfma_f32_16x16x32_bf16(alo[m], bhi, acc[m][i], 0, 0, 0);
                    acc[m][i] = __builtin_amdgcn_mfma_f32_16x16x32_bf16(ahi[m], blo, acc[m][i], 0, 0, 0);
                    acc[m][i] = __builtin_amdgcn_mfma_f32_16x16x32_bf16(ahi[m], bhi, acc[m][i], 0, 0, 0);
                }
            }
        }
        __builtin_amdgcn_s_setprio(0);
        __syncthreads();   // all waves done READING h2 -> h3 may overwrite everything
        #pragma unroll
        for (int i = 0; i < 3; ++i) {
            const int col = (nt0 + i) * 16 + (lane & 15);
            #pragma unroll
            for (int m = 0; m < 4; ++m) {
                #pragma unroll
                for (int r = 0; r < 4; ++r) {
                    const int row = m * 16 + (lane >> 4) * 4 + r;
                    int byte = (row * 768 + col * 2) ^ ((row & 7) << 4);
                    *(_Float16*)(smem + byte) = (_Float16)(acc[m][i][r]);
                }
            }
        }
    }
    __syncthreads();

    // ---- Epilogue: one thread per (row, dim); vectorized h3 read (6 x b128) ----
    const int r   = tid >> 3;         // 0..63
    const int dd  = tid & 7;
    const int row = row0 + r;
    const int swz = (r & 7) << 4;

    short8 ch[6];
    #pragma unroll
    for (int j16 = 0; j16 < 6; ++j16)
        ch[j16] = *reinterpret_cast<const short8*>(smem + ((r * 768 + dd * 96 + j16 * 16) ^ swz));
    float acc[47];
    #pragma unroll
    for (int j = 0; j < 47; ++j)
        acc[j] = (float)(((const _Float16*)&ch[j >> 3])[j & 7]);

    // unnormalized softmax exps + sums; max via v_max3 trees (exact)
    float m = max3f(max3f(max3f(acc[0], acc[1], acc[2]),
                          max3f(acc[3], acc[4], acc[5]),
                          max3f(acc[6], acc[7], acc[8])),
                    max3f(acc[9], acc[10], acc[11]),
                    max3f(max3f(acc[12], acc[13], acc[14]), acc[15], -INFINITY));
    float eW[16]; float sW = 0.0f;
    #pragma unroll
    for (int j = 0; j < 16; ++j) { eW[j] = __expf(acc[j] - m); sW += eW[j]; }

    m = max3f(max3f(max3f(acc[16], acc[17], acc[18]),
                    max3f(acc[19], acc[20], acc[21]),
                    max3f(acc[22], acc[23], acc[24])),
              max3f(acc[25], acc[26], acc[27]),
              max3f(max3f(acc[28], acc[29], acc[30]), acc[31], -INFINITY));
    float eH[16]; float sH = 0.0f;
    #pragma unroll
    for (int j = 0; j < 16; ++j) { eH[j] = __expf(acc[16 + j] - m); sH += eH[j]; }

    const float x0  = x[row * 16 + dd];
    const bool oob  = (x0 <= -5.0f) || (x0 >= 5.0f);
    const float xs  = oob ? 0.0f : x0;

    // bin search on UNNORMALIZED cumsum: xs >= -5 + 10*cum/sW  <=>  u >= cum
    const float SENT = 0.54132485f;   // softplus(SENT) == 1.0f (to float precision)
    const float u = (xs + 5.0f) * (sW * 0.1f);
    float cum = 0.0f, ycum = 0.0f;
    float selx = 0.0f, sely = 0.0f;
    float wke = eW[0], hke = eH[0];
    float d0r = SENT, d1r = acc[32];
    #pragma unroll
    for (int k = 1; k < 16; ++k) {
        cum  += eW[k - 1];
        ycum += eH[k - 1];
        if (u >= cum) {
            selx = cum; sely = ycum;
            wke = eW[k]; hke = eH[k];
            d0r = acc[31 + k];
            d1r = (k < 15) ? acc[32 + k] : SENT;
        }
    }
    // softplus on the two selected derivative logits (sentinel yields exactly ~1.0)
    const float d0 = fmaxf(d0r, 0.0f) + __logf(1.0f + __expf(-fabsf(d0r)));
    const float d1 = fmaxf(d1r, 0.0f) + __logf(1.0f + __expf(-fabsf(d1r)));

    const float invW = 10.0f * frcp(sW);
    const float invH = 10.0f * frcp(sH);
    const float xk0 = -5.0f + invW * selx;
    const float yk0 = -5.0f + invH * sely;
    const float wk  = invW * wke;
    const float hk  = invH * hke;

    const float rwk = frcp(wk);
    const float sk  = hk * rwk;
    const float t   = (xs - xk0) * rwk;
    const float omt = 1.0f - t;
    const float num = hk * (sk * t * t + d0 * t * omt);
    const float den = sk + (d1 + d0 - 2.0f * sk) * t * omt;
    const float rden = frcp(den);
    float y  = yk0 + num * rden;
    float ld = __logf(sk * sk * (d1 * t * t + 2.0f * sk * t * omt + d0 * omt * omt) * rden * rden);
    if (oob) { y = x0; ld = 0.0f; }

    ld += __shfl_xor(ld, 1);
    ld += __shfl_xor(ld, 2);
    ld += __shfl_xor(ld, 4);

    if (row < N) {
        out[row * 16 + dd]     = y;
        out[row * 16 + 8 + dd] = x[row * 16 + 8 + dd];
        if (dd == 0) out[N * 16 + row] = ld;
    }
}

extern "C" void kernel_launch(void* const* d_in, const int* in_sizes, int n_in,
                              void* d_out, int out_size, void* d_ws, size_t ws_size,
                              hipStream_t stream) {
    const float* x        = (const float*)d_in[0];
    const float* c        = (const float*)d_in[1];
    const float* bn_scale = (const float*)d_in[2];
    const float* bn_bias  = (const float*)d_in[3];
    const float* bn_mean  = (const float*)d_in[4];
    const float* bn_var   = (const float*)d_in[5];
    const float* W1       = (const float*)d_in[6];
    const float* b1       = (const float*)d_in[7];
    const float* W2       = (const float*)d_in[8];
    const float* b2       = (const float*)d_in[9];
    const float* W3       = (const float*)d_in[10];
    const float* b3       = (const float*)d_in[11];
    float* out            = (float*)d_out;
    unsigned short* wpk   = (unsigned short*)d_ws;   // needs 280576 B

    const int N = in_sizes[0] / 16;

    pack_weights<<<274, 256, 0, stream>>>(W1, W2, W3, bn_scale, bn_bias, bn_mean, bn_var,
                                          b1, b3, wpk);

    const int grid = (N + BR - 1) / BR;
    nsc_mfma<<<grid, NTHREADS, 0, stream>>>(x, c, b2, wpk, out, N);
}

// Round 15
// 125.053 us; speedup vs baseline: 1.0100x; 1.0100x over previous
//
#include <hip/hip_runtime.h>
#include <math.h>

#define NTHREADS 512
#define BR 64

typedef __attribute__((ext_vector_type(8))) short short8;
typedef __attribute__((ext_vector_type(4))) float f32x4;

// packed-weight channel layout (shorts): [0,4096) W1' | [4096,20480) W2 | [20480,69632) W3
#define W1OFF 0
#define W2OFF 4096
#define W3OFF 20480
#define WCH   69632      // shorts per channel (hi at +0, lo at +WCH)
// b1' (128 floats) at ws + 2*WCH shorts; b3' (384 floats) right after.
// ws total = 2*69632*2 + 512 + 1536 = 280576 B.

__device__ __forceinline__ unsigned short f2bf(float f) {
    unsigned u = __float_as_uint(f);
    u += 0x7fffu + ((u >> 16) & 1u);          // RNE
    return (unsigned short)(u >> 16);
}
__device__ __forceinline__ float bf2f(unsigned short h) {
    return __uint_as_float(((unsigned)h) << 16);
}
__device__ __forceinline__ float frcp(float x) { return __builtin_amdgcn_rcpf(x); }
__device__ __forceinline__ float max3f(float a, float b, float c) {
    return fmaxf(fmaxf(a, b), c);             // fuses to v_max3_f32; exactly associative
}
// truncated hi/lo split: hi = top 16 bits, lo = exact residual truncated
__device__ __forceinline__ void split2(float v, unsigned short& hi, unsigned short& lo) {
    unsigned u = __float_as_uint(v);
    hi = (unsigned short)(u >> 16);
    float lof = v - __uint_as_float(u & 0xFFFF0000u);
    lo = (unsigned short)(__float_as_uint(lof) >> 16);
}

// ---- prep: pack W1'=diag(s)W1 (16x128, K-pad 32), W2 (128x128), W3 (128x376->384
//      in 48-stride-per-dim layout) as bf16 hi/lo MFMA B-fragments; b1', b3' precomputed.
// dst for B[k][n]: base + tileIdx*512 + ((k&31)>>3)*128 + (n&15)*8 + (k&7)
__global__ void pack_weights(const float* __restrict__ W1, const float* __restrict__ W2,
                             const float* __restrict__ W3,
                             const float* __restrict__ bn_scale, const float* __restrict__ bn_bias,
                             const float* __restrict__ bn_mean, const float* __restrict__ bn_var,
                             const float* __restrict__ b1, const float* __restrict__ b3,
                             unsigned short* __restrict__ ws) {
    int idx = blockIdx.x * blockDim.x + threadIdx.x;
    if (idx >= 70144) return;
    if (idx >= 69760) {                        // b3' in 48-stride layout (pad cols -> 0)
        int n = idx - 69760;                   // n < 384
        int j = n & 47;
        ((float*)(ws + 2 * WCH))[128 + n] = (j < 47) ? b3[(n >> 4) / 3 * 47 + j] : 0.0f;
        return;
    }
    if (idx >= 69632) {                        // b1' = b1 + sum_k t_k W1[k][n]
        int n = idx - 69632;                   // n < 128
        float acc = b1[n];
        for (int k = 0; k < 16; ++k) {
            float s = bn_scale[k] * rsqrtf(bn_var[k] + 1e-5f);
            float t = bn_bias[k] - bn_mean[k] * s;
            acc += t * W1[k * 128 + n];
        }
        ((float*)(ws + 2 * WCH))[n] = acc;
        return;
    }
    int k, n, tileIdx, base;
    float v;
    if (idx < 4096) {                // W1': 32x128 (k>=16 zero), scaled by s_k
        k = idx >> 7; n = idx & 127;
        if (k < 16) {
            float s = bn_scale[k] * rsqrtf(bn_var[k] + 1e-5f);
            v = s * W1[k * 128 + n];
        } else v = 0.0f;
        base = W1OFF; tileIdx = (n >> 4);
    } else if (idx < 20480) {        // W2: 128x128
        int j = idx - 4096; k = j >> 7; n = j & 127;
        v = W2[k * 128 + n];
        base = W2OFF; tileIdx = (k >> 5) * 8 + (n >> 4);
    } else {                         // W3: 128x384, col c -> source (c/48)*47 + c%48
        int j = idx - 20480; k = j / 384; n = j - k * 384;
        int jj = n % 48, dd = n / 48;
        v = (jj < 47) ? W3[k * 376 + dd * 47 + jj] : 0.0f;
        base = W3OFF; tileIdx = (k >> 5) * 24 + (n >> 4);
    }
    int dst = base + tileIdx * 512 + ((k & 31) >> 3) * 128 + (n & 15) * 8 + (k & 7);
    unsigned short hi = f2bf(v);
    unsigned short lo = f2bf(v - bf2f(hi));
    ws[dst]       = hi;
    ws[dst + WCH] = lo;
}

// A-fragment from swizzled LDS tile h[row][128] bf16 (row stride 256B), rows 0..63
// swizzle: XOR (row&15)<<4 -> each row maps its 16 x 16B slots bijectively; the 4
// row-groups of a C/D fragment (rows +4 apart) land on 4 DISTINCT slots (2-way max).
__device__ __forceinline__ short8 ldsA(const unsigned short* h, int mt, int kt, int lane) {
    int row  = mt * 16 + (lane & 15);
    int byte = row * 256 + kt * 64 + ((lane >> 4) << 4);
    byte ^= (row & 15) << 4;
    return *reinterpret_cast<const short8*>(reinterpret_cast<const char*>(h) + byte);
}
// A-fragment from h0 [64 rows][40 shorts] (K=32 used), row stride 80B
__device__ __forceinline__ short8 ldsA0(const unsigned short* h, int mt, int lane) {
    int row  = mt * 16 + (lane & 15);
    int byte = row * 80 + ((lane >> 4) << 4);
    return *reinterpret_cast<const short8*>(reinterpret_cast<const char*>(h) + byte);
}
__device__ __forceinline__ short8 ldB(const unsigned short* w, int tileIdx, int lane) {
    return *reinterpret_cast<const short8*>(w + (tileIdx * 64 + lane) * 8);
}
__device__ __forceinline__ void stH(unsigned short* h, int row, int col, unsigned short v) {
    int byte = row * 256 + col * 2;
    byte ^= (row & 15) << 4;
    *reinterpret_cast<unsigned short*>(reinterpret_cast<char*>(h) + byte) = v;
}

__global__ __launch_bounds__(NTHREADS, 4)
void nsc_mfma(const float* __restrict__ x, const float* __restrict__ c,
              const float* __restrict__ b2,
              const unsigned short* __restrict__ wpk,
              float* __restrict__ out, int N)
{
    // LDS overlays (48 KB total):
    //   [0,16384)+[16384,32768)  h1hi/h1lo  (L1-write / L2-read)
    //   same region              h2hi/h2lo  (L2-write after read-barrier / L3-read)
    //   [32768,37888)+[37888,43008)  h0hi/h0lo  (phase A / L1; dead after)
    //   [0,49152)                h3 f16 64 x 384, row 768B, XOR-swz (row&15)<<4
    __shared__ __align__(16) char smem[49152];
    unsigned short* h1hi = (unsigned short*)(smem);
    unsigned short* h1lo = (unsigned short*)(smem + 16384);
    unsigned short* h2hi = (unsigned short*)(smem);           // overlays h1 (read-barrier'd)
    unsigned short* h2lo = (unsigned short*)(smem + 16384);
    unsigned short* h0hi = (unsigned short*)(smem + 32768);
    unsigned short* h0lo = (unsigned short*)(smem + 37888);

    const unsigned short* wlo = wpk + WCH;
    const float* b1p = (const float*)(wpk + 2 * WCH);
    const float* b3p = b1p + 128;

    const int tid  = threadIdx.x;
    const int lane = tid & 63;
    const int wv   = tid >> 6;        // 8 waves; each wave covers M=64 (all 4 mt) x N/8
    const int row0 = blockIdx.x * BR;

    // ---- Phase A (vectorized): h0 = raw hstack([upper, c]) -> bf16 hi/lo ----
    {
        const int r  = tid >> 3;      // 0..63
        const int p  = tid & 7;       // col-pair index: cols 2p, 2p+1
        int row = row0 + r; if (row >= N) row = N - 1;
        const float2 v2 = (p < 4)
            ? *reinterpret_cast<const float2*>(x + row * 16 + 8 + 2 * p)
            : *reinterpret_cast<const float2*>(c + row * 8 + 2 * (p - 4));
        unsigned short hi0, lo0, hi1, lo1;
        split2(v2.x, hi0, lo0);
        split2(v2.y, hi1, lo1);
        const int base = r * 40 + 2 * p;
        *reinterpret_cast<unsigned*>(h0hi + base) = (unsigned)hi0 | ((unsigned)hi1 << 16);
        *reinterpret_cast<unsigned*>(h0lo + base) = (unsigned)lo0 | ((unsigned)lo1 << 16);
        *reinterpret_cast<unsigned*>(h0hi + base + 16) = 0u;   // K pad cols 16..31
        *reinterpret_cast<unsigned*>(h0lo + base + 16) = 0u;
    }
    __syncthreads();

    // ---- Layer 1 (MFMA split): h1 = swish(h0 @ W1' + b1'), bias in acc init ----
    {
        const int col = wv * 16 + (lane & 15);
        const float bias = b1p[col];
        f32x4 acc[4];
        #pragma unroll
        for (int m = 0; m < 4; ++m) acc[m] = (f32x4){bias, bias, bias, bias};
        short8 bhi = ldB(wpk + W1OFF, wv, lane);
        short8 blo = ldB(wlo + W1OFF, wv, lane);
        __builtin_amdgcn_s_setprio(1);
        #pragma unroll
        for (int m = 0; m < 4; ++m) {
            short8 ahi = ldsA0(h0hi, m, lane);
            short8 alo = ldsA0(h0lo, m, lane);
            acc[m] = __builtin_amdgcn_mfma_f32_16x16x32_bf16(alo, bhi, acc[m], 0, 0, 0);
            acc[m] = __builtin_amdgcn_mfma_f32_16x16x32_bf16(ahi, blo, acc[m], 0, 0, 0);
            acc[m] = __builtin_amdgcn_mfma_f32_16x16x32_bf16(ahi, bhi, acc[m], 0, 0, 0);
        }
        __builtin_amdgcn_s_setprio(0);
        #pragma unroll
        for (int m = 0; m < 4; ++m) {
            #pragma unroll
            for (int r = 0; r < 4; ++r) {
                const int row = m * 16 + (lane >> 4) * 4 + r;
                float v = acc[m][r];
                v = v * frcp(1.0f + __expf(-v));
                unsigned short hi, lo; split2(v, hi, lo);
                stH(h1hi, row, col, hi);
                stH(h1lo, row, col, lo);
            }
        }
    }
    __syncthreads();   // h1 ready; h0 dead after L1's reads

    // ---- Layer 2 (MFMA split): h2 = swish(h1 @ W2 + b2); h2 OVERLAYS h1 after read-barrier ----
    {
        const int col = wv * 16 + (lane & 15);
        const float bias = b2[col];
        f32x4 acc[4];
        #pragma unroll
        for (int m = 0; m < 4; ++m) acc[m] = (f32x4){bias, bias, bias, bias};
        __builtin_amdgcn_s_setprio(1);
        #pragma unroll
        for (int kt = 0; kt < 4; ++kt) {
            short8 bhi = ldB(wpk + W2OFF, kt * 8 + wv, lane);
            short8 blo = ldB(wlo + W2OFF, kt * 8 + wv, lane);
            #pragma unroll
            for (int m = 0; m < 4; ++m) {
                short8 ahi = ldsA(h1hi, m, kt, lane);
                short8 alo = ldsA(h1lo, m, kt, lane);
                acc[m] = __builtin_amdgcn_mfma_f32_16x16x32_bf16(alo, bhi, acc[m], 0, 0, 0);
                acc[m] = __builtin_amdgcn_mfma_f32_16x16x32_bf16(ahi, blo, acc[m], 0, 0, 0);
                acc[m] = __builtin_amdgcn_mfma_f32_16x16x32_bf16(ahi, bhi, acc[m], 0, 0, 0);
            }
        }
        __builtin_amdgcn_s_setprio(0);
        __syncthreads();   // ALL waves done reading h1 -> h2 may overwrite the region
        #pragma unroll
        for (int m = 0; m < 4; ++m) {
            #pragma unroll
            for (int r = 0; r < 4; ++r) {
                const int row = m * 16 + (lane >> 4) * 4 + r;
                float v = acc[m][r];
                v = v * frcp(1.0f + __expf(-v));
                unsigned short hi, lo; split2(v, hi, lo);
                stH(h2hi, row, col, hi);
                stH(h2lo, row, col, lo);
            }
        }
    }
    __syncthreads();

    // ---- Layer 3 (MFMA split): M=64/wave, nt = wv*3+{0..2}; bias in acc init ----
    {
        const int nt0 = wv * 3;
        float biasv[3];
        #pragma unroll
        for (int i = 0; i < 3; ++i) biasv[i] = b3p[(nt0 + i) * 16 + (lane & 15)];
        f32x4 acc[4][3];
        #pragma unroll
        for (int m = 0; m < 4; ++m)
            #pragma unroll
            for (int i = 0; i < 3; ++i)
                acc[m][i] = (f32x4){biasv[i], biasv[i], biasv[i], biasv[i]};
        __builtin_amdgcn_s_setprio(1);
        #pragma unroll
        for (int kt = 0; kt < 4; ++kt) {
            short8 ahi[4], alo[4];
            #pragma unroll
            for (int m = 0; m < 4; ++m) { ahi[m] = ldsA(h2hi, m, kt, lane); alo[m] = ldsA(h2lo, m, kt, lane); }
            #pragma unroll
            for (int i = 0; i < 3; ++i) {
                const int t = kt * 24 + nt0 + i;
                short8 bhi = ldB(wpk + W3OFF, t, lane);
                short8 blo = ldB(wlo + W3OFF, t, lane);
                #pragma unroll
                for (int m = 0; m < 4; ++m) {
                    acc[m][i] = __builtin_amdgcn_mfma_f32_16x16x32_bf16(alo[m], bhi, acc[m][i], 0, 0, 0);
                    acc[m][i] = __builtin_amdgcn_mfma_f32_16x16x32_bf16(ahi[m], blo, acc[m][i], 0, 0, 0);
                    acc[m][i] = __builtin_amdgcn_mfma_f32_16x16x32_bf16(ahi[m], bhi, acc[m][i], 0, 0, 0);
                }
            }
        }
        __builtin_amdgcn_s_setprio(0);
        __syncthreads();   // all waves done READING h2 -> h3 may overwrite everything
        #pragma unroll
        for (int i = 0; i < 3; ++i) {
            const int col = (nt0 + i) * 16 + (lane & 15);
            #pragma unroll
            for (int m = 0; m < 4; ++m) {
                #pragma unroll
                for (int r = 0; r < 4; ++r) {
                    const int row = m * 16 + (lane >> 4) * 4 + r;
                    int byte = (row * 768 + col * 2) ^ ((row & 15) << 4);
                    *(_Float16*)(smem + byte) = (_Float16)(acc[m][i][r]);
                }
            }
        }
    }
    __syncthreads();

    // ---- Epilogue: one thread per (row, dim); vectorized h3 read (6 x b128) ----
    const int r   = tid >> 3;         // 0..63
    const int dd  = tid & 7;
    const int row = row0 + r;
    const int swz = (r & 15) << 4;

    short8 ch[6];
    #pragma unroll
    for (int j16 = 0; j16 < 6; ++j16)
        ch[j16] = *reinterpret_cast<const short8*>(smem + ((r * 768 + dd * 96 + j16 * 16) ^ swz));
    float acc[47];
    #pragma unroll
    for (int j = 0; j < 47; ++j)
        acc[j] = (float)(((const _Float16*)&ch[j >> 3])[j & 7]);

    // unnormalized softmax exps + sums; max via v_max3 trees (exact)
    float m = max3f(max3f(max3f(acc[0], acc[1], acc[2]),
                          max3f(acc[3], acc[4], acc[5]),
                          max3f(acc[6], acc[7], acc[8])),
                    max3f(acc[9], acc[10], acc[11]),
                    max3f(max3f(acc[12], acc[13], acc[14]), acc[15], -INFINITY));
    float eW[16]; float sW = 0.0f;
    #pragma unroll
    for (int j = 0; j < 16; ++j) { eW[j] = __expf(acc[j] - m); sW += eW[j]; }

    m = max3f(max3f(max3f(acc[16], acc[17], acc[18]),
                    max3f(acc[19], acc[20], acc[21]),
                    max3f(acc[22], acc[23], acc[24])),
              max3f(acc[25], acc[26], acc[27]),
              max3f(max3f(acc[28], acc[29], acc[30]), acc[31], -INFINITY));
    float eH[16]; float sH = 0.0f;
    #pragma unroll
    for (int j = 0; j < 16; ++j) { eH[j] = __expf(acc[16 + j] - m); sH += eH[j]; }

    const float x0  = x[row * 16 + dd];
    const bool oob  = (x0 <= -5.0f) || (x0 >= 5.0f);
    const float xs  = oob ? 0.0f : x0;

    // bin search on UNNORMALIZED cumsum: xs >= -5 + 10*cum/sW  <=>  u >= cum
    const float SENT = 0.54132485f;   // softplus(SENT) == 1.0f (to float precision)
    const float u = (xs + 5.0f) * (sW * 0.1f);
    float cum = 0.0f, ycum = 0.0f;
    float selx = 0.0f, sely = 0.0f;
    float wke = eW[0], hke = eH[0];
    float d0r = SENT, d1r = acc[32];
    #pragma unroll
    for (int k = 1; k < 16; ++k) {
        cum  += eW[k - 1];
        ycum += eH[k - 1];
        if (u >= cum) {
            selx = cum; sely = ycum;
            wke = eW[k]; hke = eH[k];
            d0r = acc[31 + k];
            d1r = (k < 15) ? acc[32 + k] : SENT;
        }
    }
    // softplus on the two selected derivative logits (sentinel yields exactly ~1.0)
    const float d0 = fmaxf(d0r, 0.0f) + __logf(1.0f + __expf(-fabsf(d0r)));
    const float d1 = fmaxf(d1r, 0.0f) + __logf(1.0f + __expf(-fabsf(d1r)));

    const float invW = 10.0f * frcp(sW);
    const float invH = 10.0f * frcp(sH);
    const float xk0 = -5.0f + invW * selx;
    const float yk0 = -5.0f + invH * sely;
    const float wk  = invW * wke;
    const float hk  = invH * hke;

    const float rwk = frcp(wk);
    const float sk  = hk * rwk;
    const float t   = (xs - xk0) * rwk;
    const float omt = 1.0f - t;
    const float num = hk * (sk * t * t + d0 * t * omt);
    const float den = sk + (d1 + d0 - 2.0f * sk) * t * omt;
    const float rden = frcp(den);
    float y  = yk0 + num * rden;
    float ld = __logf(sk * sk * (d1 * t * t + 2.0f * sk * t * omt + d0 * omt * omt) * rden * rden);
    if (oob) { y = x0; ld = 0.0f; }

    ld += __shfl_xor(ld, 1);
    ld += __shfl_xor(ld, 2);
    ld += __shfl_xor(ld, 4);

    if (row < N) {
        out[row * 16 + dd]     = y;
        out[row * 16 + 8 + dd] = x[row * 16 + 8 + dd];
        if (dd == 0) out[N * 16 + row] = ld;
    }
}

extern "C" void kernel_launch(void* const* d_in, const int* in_sizes, int n_in,
                              void* d_out, int out_size, void* d_ws, size_t ws_size,
                              hipStream_t stream) {
    const float* x        = (const float*)d_in[0];
    const float* c        = (const float*)d_in[1];
    const float* bn_scale = (const float*)d_in[2];
    const float* bn_bias  = (const float*)d_in[3];
    const float* bn_mean  = (const float*)d_in[4];
    const float* bn_var   = (const float*)d_in[5];
    const float* W1       = (const float*)d_in[6];
    const float* b1       = (const float*)d_in[7];
    const float* W2       = (const float*)d_in[8];
    const float* b2       = (const float*)d_in[9];
    const float* W3       = (const float*)d_in[10];
    const float* b3       = (const float*)d_in[11];
    float* out            = (float*)d_out;
    unsigned short* wpk   = (unsigned short*)d_ws;   // needs 280576 B

    const int N = in_sizes[0] / 16;

    pack_weights<<<274, 256, 0, stream>>>(W1, W2, W3, bn_scale, bn_bias, bn_mean, bn_var,
                                          b1, b3, wpk);

    const int grid = (N + BR - 1) / BR;
    nsc_mfma<<<grid, NTHREADS, 0, stream>>>(x, c, b2, wpk, out, N);
}